// Round 2
// baseline (1271.028 us; speedup 1.0000x reference)
//
#include <hip/hip_runtime.h>
#include <hip/hip_fp16.h>
#include <math.h>

#define N_NODES 100000
#define N_EDGES 1600000
#define ETOT    (N_EDGES + N_NODES)
#define NHEAD   4
#define ED      8

// ---------------- CSR build (graph shared by both layers) ----------------

__global__ void count_kernel(const int* __restrict__ ei, int* __restrict__ counts) {
    int e = blockIdx.x * 256 + threadIdx.x;
    if (e >= ETOT) return;
    int d = (e < N_EDGES) ? ei[N_EDGES + e] : (e - N_EDGES);
    atomicAdd(&counts[d], 1);
}

#define SCAN_CHUNK 1024
#define SCAN_NB    ((N_NODES + SCAN_CHUNK - 1) / SCAN_CHUNK)   // 98

__global__ void scan1_kernel(const int* __restrict__ counts, int* __restrict__ rowptr,
                             int* __restrict__ bsum) {
    __shared__ int tmp[SCAN_CHUNK];
    int t = threadIdx.x;
    int i = blockIdx.x * SCAN_CHUNK + t;
    int v = (i < N_NODES) ? counts[i] : 0;
    tmp[t] = v;
    __syncthreads();
    for (int off = 1; off < SCAN_CHUNK; off <<= 1) {
        int x = (t >= off) ? tmp[t - off] : 0;
        __syncthreads();
        tmp[t] += x;
        __syncthreads();
    }
    if (i < N_NODES) rowptr[i] = tmp[t] - v;
    if (t == SCAN_CHUNK - 1) bsum[blockIdx.x] = tmp[t];
}

__global__ void scan2_kernel(int* __restrict__ bsum) {
    if (threadIdx.x == 0 && blockIdx.x == 0) {
        int run = 0;
        for (int b = 0; b < SCAN_NB; ++b) { int t = bsum[b]; bsum[b] = run; run += t; }
    }
}

__global__ void scan3_kernel(int* __restrict__ rowptr, const int* __restrict__ bsum,
                             int* __restrict__ cursor) {
    int i = blockIdx.x * SCAN_CHUNK + threadIdx.x;
    if (i < N_NODES) {
        int v = rowptr[i] + bsum[blockIdx.x];
        rowptr[i] = v;
        cursor[i] = v;
    }
    if (i == 0) rowptr[N_NODES] = ETOT;
}

// writes esrc (CSR order) and pos[e] = CSR slot of edge e (coalesced by e)
__global__ void fill_kernel(const int* __restrict__ ei, int* __restrict__ cursor,
                            int* __restrict__ esrc, int* __restrict__ pos) {
    int e = blockIdx.x * 256 + threadIdx.x;
    if (e >= ETOT) return;
    int s, d;
    if (e < N_EDGES) { s = ei[e]; d = ei[N_EDGES + e]; }
    else             { s = e - N_EDGES; d = s; }
    int p = atomicAdd(&cursor[d], 1);
    esrc[p] = s;
    pos[e]  = p;
}

// ---------------- fold We/a_edge into M[8][4] ----------------

__global__ void make_M(const float* __restrict__ We, const float* __restrict__ a_edge,
                       float* __restrict__ M, int C) {
    int t = threadIdx.x;
    if (t >= ED * NHEAD) return;
    int d = t >> 2, h = t & 3;
    float s = 0.f;
    for (int c = 0; c < C; ++c) s += We[d * (NHEAD * C) + h * C + c] * a_edge[h * C + c];
    M[d * NHEAD + h] = s;
}

// ---------------- h = x @ W + per-node attention scalars ----------------
// 256-thread block handles NPB nodes; each thread computes 4 output channels.

template <int FIN, int C, typename HT>
__global__ __launch_bounds__(256) void feat_kernel(
    const float* __restrict__ x, const float* __restrict__ W,
    const float* __restrict__ a_src, const float* __restrict__ a_dst,
    HT* __restrict__ h, float* __restrict__ as_n, float* __restrict__ ad_n) {
    constexpr int CH  = NHEAD * C;
    constexpr int TPN = CH / 4;        // threads per node
    constexpr int NPB = 256 / TPN;     // nodes per block
    __shared__ float xs[NPB][FIN + 1];
    int t = threadIdx.x;
    int ln = t / TPN;
    int ct = t % TPN;
    int nbase = blockIdx.x * NPB;
    for (int i = t; i < NPB * FIN; i += 256) {
        int nn = i / FIN, dd = i % FIN;
        int gn = nbase + nn;
        xs[nn][dd] = (gn < N_NODES) ? x[(size_t)gn * FIN + dd] : 0.f;
    }
    __syncthreads();
    int n = nbase + ln;
    if (n >= N_NODES) return;
    float a0 = 0, a1 = 0, a2 = 0, a3 = 0;
    const float* wp = W + ct * 4;
#pragma unroll
    for (int dd = 0; dd < FIN; ++dd) {
        float xv = xs[ln][dd];
        float4 wv = *reinterpret_cast<const float4*>(wp + (size_t)dd * CH);
        a0 += xv * wv.x; a1 += xv * wv.y; a2 += xv * wv.z; a3 += xv * wv.w;
    }
    if constexpr (sizeof(HT) == 2) {
        __half2 p01 = __floats2half2_rn(a0, a1);
        __half2 p23 = __floats2half2_rn(a2, a3);
        __half2* hp = reinterpret_cast<__half2*>(
            reinterpret_cast<__half*>(h) + (size_t)n * CH + ct * 4);
        hp[0] = p01; hp[1] = p23;
    } else {
        *reinterpret_cast<float4*>(reinterpret_cast<float*>(h) + (size_t)n * CH + ct * 4)
            = make_float4(a0, a1, a2, a3);
    }
    int c4 = ct * 4;   // global channel index == flat index into a_src/a_dst [H*C]
    float sa = a0 * a_src[c4] + a1 * a_src[c4 + 1] + a2 * a_src[c4 + 2] + a3 * a_src[c4 + 3];
    float sd = a0 * a_dst[c4] + a1 * a_dst[c4 + 1] + a2 * a_dst[c4 + 2] + a3 * a_dst[c4 + 3];
    constexpr int GRP = C / 4;        // threads covering one head
#pragma unroll
    for (int off = GRP / 2; off > 0; off >>= 1) {
        sa += __shfl_xor(sa, off);
        sd += __shfl_xor(sd, off);
    }
    if ((ct & (GRP - 1)) == 0) {
        int head = ct / GRP;
        as_n[(size_t)n * NHEAD + head] = sa;
        ad_n[(size_t)n * NHEAD + head] = sd;
    }
}

// ---------------- edge pass: ex = exp(leaky(alpha)), scattered to CSR order ----------------
// No max subtraction needed: |alpha| <~ 15, exp safe in f32; softmax ratio identical.

__global__ __launch_bounds__(256) void alpha_kernel(
    const int* __restrict__ ei, const float* __restrict__ ea,
    const float* __restrict__ as_n, const float* __restrict__ ad_n,
    const float* __restrict__ M, const int* __restrict__ pos,
    float* __restrict__ exw, float* __restrict__ denom) {
    int e = blockIdx.x * 256 + threadIdx.x;
    if (e >= ETOT) return;
    int s, d;
    float ae0 = 0, ae1 = 0, ae2 = 0, ae3 = 0;
    if (e < N_EDGES) {
        s = ei[e]; d = ei[N_EDGES + e];
        const float4* er = reinterpret_cast<const float4*>(ea + (size_t)e * ED);
        float4 A = er[0], B = er[1];
        float ev[8] = {A.x, A.y, A.z, A.w, B.x, B.y, B.z, B.w};
#pragma unroll
        for (int dd = 0; dd < 8; ++dd) {
            float xv = ev[dd];
            ae0 += xv * M[dd * 4 + 0];
            ae1 += xv * M[dd * 4 + 1];
            ae2 += xv * M[dd * 4 + 2];
            ae3 += xv * M[dd * 4 + 3];
        }
    } else {
        s = e - N_EDGES; d = s;
    }
    float4 av = *reinterpret_cast<const float4*>(as_n + (size_t)s * 4);
    float4 bv = *reinterpret_cast<const float4*>(ad_n + (size_t)d * 4);
    float al[4] = {av.x + bv.x + ae0, av.y + bv.y + ae1,
                   av.z + bv.z + ae2, av.w + bv.w + ae3};
    float ex[4];
#pragma unroll
    for (int hh = 0; hh < 4; ++hh) {
        float a = al[hh];
        a = (a > 0.f) ? a : 0.2f * a;
        ex[hh] = __expf(a);
    }
    int p = pos[e];
    *reinterpret_cast<float4*>(exw + (size_t)p * 4) = make_float4(ex[0], ex[1], ex[2], ex[3]);
    atomicAdd(&denom[d * 4 + 0], ex[0]);
    atomicAdd(&denom[d * 4 + 1], ex[1]);
    atomicAdd(&denom[d * 4 + 2], ex[2]);
    atomicAdd(&denom[d * 4 + 3], ex[3]);
}

// ---------------- aggregation: one wave per dst node, pure weighted gather ----------------

template <int C, typename HT>
__global__ __launch_bounds__(256) void gat_aggregate(
    const int* __restrict__ rowptr, const int* __restrict__ esrc,
    const float* __restrict__ exw, const void* __restrict__ hbuf,
    const float* __restrict__ denom, const float* __restrict__ bias,
    float* __restrict__ out) {
    constexpr int FPL = (NHEAD * C) / 64;   // 2 (fp16 L1) or 1 (f32 L2)
    int lane = threadIdx.x & 63;
    int n = blockIdx.x * 4 + (threadIdx.x >> 6);
    if (n >= N_NODES) return;
    int head = lane >> 4;
    const __half2* h16 = reinterpret_cast<const __half2*>(hbuf);
    const float*   h32 = reinterpret_cast<const float*>(hbuf);

    int p0 = __builtin_amdgcn_readfirstlane(rowptr[n]);
    int p1 = __builtin_amdgcn_readfirstlane(rowptr[n + 1]);

    float acc0[FPL], acc1[FPL], acc2[FPL], acc3[FPL];
#pragma unroll
    for (int k = 0; k < FPL; ++k) { acc0[k] = 0; acc1[k] = 0; acc2[k] = 0; acc3[k] = 0; }

    auto LOADH = [&](int sp, float* v) {
        if constexpr (C == 32) {
            float2 f = __half22float2(h16[(size_t)sp * 64 + lane]);
            v[0] = f.x; v[1] = f.y;
        } else {
            v[0] = h32[(size_t)sp * 64 + lane];
        }
    };

    int p = p0;
    for (; p + 3 < p1; p += 4) {
        int s0 = esrc[p], s1 = esrc[p + 1], s2 = esrc[p + 2], s3 = esrc[p + 3];
        float w0 = exw[(size_t)p * 4 + head];
        float w1 = exw[(size_t)(p + 1) * 4 + head];
        float w2 = exw[(size_t)(p + 2) * 4 + head];
        float w3 = exw[(size_t)(p + 3) * 4 + head];
        float v0[FPL], v1[FPL], v2[FPL], v3[FPL];
        LOADH(s0, v0); LOADH(s1, v1); LOADH(s2, v2); LOADH(s3, v3);
#pragma unroll
        for (int k = 0; k < FPL; ++k) {
            acc0[k] += w0 * v0[k];
            acc1[k] += w1 * v1[k];
            acc2[k] += w2 * v2[k];
            acc3[k] += w3 * v3[k];
        }
    }
    for (; p < p1; ++p) {
        int s0 = esrc[p];
        float w0 = exw[(size_t)p * 4 + head];
        float v0[FPL]; LOADH(s0, v0);
#pragma unroll
        for (int k = 0; k < FPL; ++k) acc0[k] += w0 * v0[k];
    }

    float inv = 1.f / (denom[(size_t)n * 4 + head] + 1e-16f);
    float v[FPL];
#pragma unroll
    for (int k = 0; k < FPL; ++k)
        v[k] = ((acc0[k] + acc1[k]) + (acc2[k] + acc3[k])) * inv;
    // head mean: lanes l, l^16, l^32, l^48 hold the same within-head column
#pragma unroll
    for (int k = 0; k < FPL; ++k) {
        v[k] += __shfl_xor(v[k], 16);
        v[k] += __shfl_xor(v[k], 32);
    }
    if (lane < 16) {
#pragma unroll
        for (int k = 0; k < FPL; ++k) {
            int c = lane * FPL + k;
            float o = 0.25f * v[k] + bias[c];
            o = (o > 0.f) ? o : expm1f(o);
            out[(size_t)n * C + c] = o;
        }
    }
}

// ---------------- launch ----------------

static inline size_t align_up(size_t x, size_t a) { return (x + a - 1) & ~(a - 1); }

extern "C" void kernel_launch(void* const* d_in, const int* in_sizes, int n_in,
                              void* d_out, int out_size, void* d_ws, size_t ws_size,
                              hipStream_t stream) {
    const float* x       = (const float*)d_in[0];
    const int*   ei      = (const int*)d_in[1];
    const float* ea      = (const float*)d_in[2];
    const float* W1      = (const float*)d_in[3];
    const float* We1     = (const float*)d_in[4];
    const float* a_src1  = (const float*)d_in[5];
    const float* a_dst1  = (const float*)d_in[6];
    const float* a_edge1 = (const float*)d_in[7];
    const float* b1      = (const float*)d_in[8];
    const float* W2      = (const float*)d_in[9];
    const float* We2     = (const float*)d_in[10];
    const float* a_src2  = (const float*)d_in[11];
    const float* a_dst2  = (const float*)d_in[12];
    const float* a_edge2 = (const float*)d_in[13];
    const float* b2      = (const float*)d_in[14];
    float* out = (float*)d_out;

    char* p = (char*)d_ws;
    auto take = [&](size_t bytes) { char* r = p; p += align_up(bytes, 256); return r; };
    int*   counts = (int*)take(sizeof(int) * N_NODES);
    int*   rowptr = (int*)take(sizeof(int) * (N_NODES + 1));
    int*   cursor = (int*)take(sizeof(int) * N_NODES);
    int*   bsum   = (int*)take(sizeof(int) * 128);
    int*   esrc   = (int*)take(sizeof(int) * ETOT);
    int*   pos    = (int*)take(sizeof(int) * ETOT);
    float* exw    = (float*)take(sizeof(float) * (size_t)ETOT * NHEAD);   // 27.2 MB
    float* denomP = (float*)take(sizeof(float) * (size_t)N_NODES * NHEAD * 2);
    float* denom1 = denomP;
    float* denom2 = denomP + (size_t)N_NODES * NHEAD;
    float* as_n   = (float*)take(sizeof(float) * N_NODES * NHEAD);
    float* ad_n   = (float*)take(sizeof(float) * N_NODES * NHEAD);
    void*  hbuf   = (void*)take((size_t)N_NODES * 128 * 2);               // 25.6 MB, fp16 L1 / f32 L2
    float* x2     = (float*)take(sizeof(float) * (size_t)N_NODES * 32);
    float* M1     = (float*)take(sizeof(float) * ED * NHEAD);
    float* M2     = (float*)take(sizeof(float) * ED * NHEAD);

    hipMemsetAsync(counts, 0, sizeof(int) * N_NODES, stream);
    hipMemsetAsync(denomP, 0, sizeof(float) * (size_t)N_NODES * NHEAD * 2, stream);

    int egrid = (ETOT + 255) / 256;
    count_kernel<<<egrid, 256, 0, stream>>>(ei, counts);
    scan1_kernel<<<SCAN_NB, SCAN_CHUNK, 0, stream>>>(counts, rowptr, bsum);
    scan2_kernel<<<1, 1, 0, stream>>>(bsum);
    scan3_kernel<<<SCAN_NB, SCAN_CHUNK, 0, stream>>>(rowptr, bsum, cursor);
    fill_kernel<<<egrid, 256, 0, stream>>>(ei, cursor, esrc, pos);

    make_M<<<1, 32, 0, stream>>>(We1, a_edge1, M1, 32);
    make_M<<<1, 32, 0, stream>>>(We2, a_edge2, M2, 16);

    int ngrid = N_NODES / 4;   // 25000

    // ---- layer 1: Fin=64, C=32, h stored fp16 ----
    feat_kernel<64, 32, __half><<<(N_NODES + 7) / 8, 256, 0, stream>>>(
        x, W1, a_src1, a_dst1, (__half*)hbuf, as_n, ad_n);
    alpha_kernel<<<egrid, 256, 0, stream>>>(ei, ea, as_n, ad_n, M1, pos, exw, denom1);
    gat_aggregate<32, __half><<<ngrid, 256, 0, stream>>>(rowptr, esrc, exw, hbuf,
                                                         denom1, b1, x2);

    // ---- layer 2: Fin=32, C=16, h stored f32 ----
    feat_kernel<32, 16, float><<<(N_NODES + 15) / 16, 256, 0, stream>>>(
        x2, W2, a_src2, a_dst2, (float*)hbuf, as_n, ad_n);
    alpha_kernel<<<egrid, 256, 0, stream>>>(ei, ea, as_n, ad_n, M2, pos, exw, denom2);
    gat_aggregate<16, float><<<ngrid, 256, 0, stream>>>(rowptr, esrc, exw, hbuf,
                                                        denom2, b2, out);
}

// Round 4
// 877.460 us; speedup vs baseline: 1.4485x; 1.4485x over previous
//
#include <hip/hip_runtime.h>
#include <hip/hip_fp16.h>
#include <math.h>

#define N_NODES 100000
#define N_EDGES 1600000
#define ETOT    (N_EDGES + N_NODES)
#define NHEAD   4
#define ED      8

// ---------------- CSR build (graph shared by both layers) ----------------

__global__ void count_kernel(const int* __restrict__ ei, int* __restrict__ counts) {
    int e = blockIdx.x * 256 + threadIdx.x;
    if (e >= ETOT) return;
    int d = (e < N_EDGES) ? ei[N_EDGES + e] : (e - N_EDGES);
    atomicAdd(&counts[d], 1);
}

#define SCAN_CHUNK 1024
#define SCAN_NB    ((N_NODES + SCAN_CHUNK - 1) / SCAN_CHUNK)   // 98

__global__ void scan1_kernel(const int* __restrict__ counts, int* __restrict__ rowptr,
                             int* __restrict__ bsum) {
    __shared__ int tmp[SCAN_CHUNK];
    int t = threadIdx.x;
    int i = blockIdx.x * SCAN_CHUNK + t;
    int v = (i < N_NODES) ? counts[i] : 0;
    tmp[t] = v;
    __syncthreads();
    for (int off = 1; off < SCAN_CHUNK; off <<= 1) {
        int x = (t >= off) ? tmp[t - off] : 0;
        __syncthreads();
        tmp[t] += x;
        __syncthreads();
    }
    if (i < N_NODES) rowptr[i] = tmp[t] - v;
    if (t == SCAN_CHUNK - 1) bsum[blockIdx.x] = tmp[t];
}

__global__ void scan2_kernel(int* __restrict__ bsum) {
    if (threadIdx.x == 0 && blockIdx.x == 0) {
        int run = 0;
        for (int b = 0; b < SCAN_NB; ++b) { int t = bsum[b]; bsum[b] = run; run += t; }
    }
}

__global__ void scan3_kernel(int* __restrict__ rowptr, const int* __restrict__ bsum,
                             int* __restrict__ cursor) {
    int i = blockIdx.x * SCAN_CHUNK + threadIdx.x;
    if (i < N_NODES) {
        int v = rowptr[i] + bsum[blockIdx.x];
        rowptr[i] = v;
        cursor[i] = v;
    }
    if (i == 0) rowptr[N_NODES] = ETOT;
}

__global__ void fill_kernel(const int* __restrict__ ei, int* __restrict__ cursor,
                            int* __restrict__ esrc, int* __restrict__ eid) {
    int e = blockIdx.x * 256 + threadIdx.x;
    if (e >= ETOT) return;
    int s, d;
    if (e < N_EDGES) { s = ei[e]; d = ei[N_EDGES + e]; }
    else             { s = e - N_EDGES; d = s; }
    int p = atomicAdd(&cursor[d], 1);
    esrc[p] = s;
    eid[p]  = e;
}

// ---------------- fold We/a_edge into M[8][4] ----------------

__global__ void make_M(const float* __restrict__ We, const float* __restrict__ a_edge,
                       float* __restrict__ M, int C) {
    int t = threadIdx.x;
    if (t >= ED * NHEAD) return;
    int d = t >> 2, h = t & 3;
    float s = 0.f;
    for (int c = 0; c < C; ++c) s += We[d * (NHEAD * C) + h * C + c] * a_edge[h * C + c];
    M[d * NHEAD + h] = s;
}

// ---------------- h = x @ W + per-node attention scalars ----------------

template <int FIN, int C, typename HT>
__global__ __launch_bounds__(256) void feat_kernel(
    const float* __restrict__ x, const float* __restrict__ W,
    const float* __restrict__ a_src, const float* __restrict__ a_dst,
    HT* __restrict__ h, float* __restrict__ as_n, float* __restrict__ ad_n) {
    constexpr int CH  = NHEAD * C;
    constexpr int TPN = CH / 4;        // threads per node
    constexpr int NPB = 256 / TPN;     // nodes per block
    __shared__ float xs[NPB][FIN + 1];
    int t = threadIdx.x;
    int ln = t / TPN;
    int ct = t % TPN;
    int nbase = blockIdx.x * NPB;
    for (int i = t; i < NPB * FIN; i += 256) {
        int nn = i / FIN, dd = i % FIN;
        int gn = nbase + nn;
        xs[nn][dd] = (gn < N_NODES) ? x[(size_t)gn * FIN + dd] : 0.f;
    }
    __syncthreads();
    int n = nbase + ln;
    if (n >= N_NODES) return;
    float a0 = 0, a1 = 0, a2 = 0, a3 = 0;
    const float* wp = W + ct * 4;
#pragma unroll
    for (int dd = 0; dd < FIN; ++dd) {
        float xv = xs[ln][dd];
        float4 wv = *reinterpret_cast<const float4*>(wp + (size_t)dd * CH);
        a0 += xv * wv.x; a1 += xv * wv.y; a2 += xv * wv.z; a3 += xv * wv.w;
    }
    if constexpr (sizeof(HT) == 2) {
        __half2 p01 = __floats2half2_rn(a0, a1);
        __half2 p23 = __floats2half2_rn(a2, a3);
        __half2* hp = reinterpret_cast<__half2*>(
            reinterpret_cast<__half*>(h) + (size_t)n * CH + ct * 4);
        hp[0] = p01; hp[1] = p23;
    } else {
        *reinterpret_cast<float4*>(reinterpret_cast<float*>(h) + (size_t)n * CH + ct * 4)
            = make_float4(a0, a1, a2, a3);
    }
    int c4 = ct * 4;
    float sa = a0 * a_src[c4] + a1 * a_src[c4 + 1] + a2 * a_src[c4 + 2] + a3 * a_src[c4 + 3];
    float sd = a0 * a_dst[c4] + a1 * a_dst[c4 + 1] + a2 * a_dst[c4 + 2] + a3 * a_dst[c4 + 3];
    constexpr int GRP = C / 4;
#pragma unroll
    for (int off = GRP / 2; off > 0; off >>= 1) {
        sa += __shfl_xor(sa, off);
        sd += __shfl_xor(sd, off);
    }
    if ((ct & (GRP - 1)) == 0) {
        int head = ct / GRP;
        as_n[(size_t)n * NHEAD + head] = sa;
        ad_n[(size_t)n * NHEAD + head] = sd;
    }
}

// ---------------- fused alpha + aggregation: one wave per dst node ----------------
// w_e = exp(leaky(as[src]+ad[dst]+ea[e]·M)) computed inline (no max-subtraction
// needed: |alpha| small, exp safe in f32; softmax ratio unchanged). No serial
// dependence -> unroll 4 with independent accumulators, 4 gather chains in flight.

template <int C, typename HT>
__global__ __launch_bounds__(256) void gat_fused(
    const int* __restrict__ rowptr, const int* __restrict__ esrc,
    const int* __restrict__ eid, const void* __restrict__ hbuf,
    const float* __restrict__ as_n, const float* __restrict__ ad_n,
    const float* __restrict__ ea, const float* __restrict__ M,
    const float* __restrict__ bias, float* __restrict__ out) {
    constexpr int FPL = (NHEAD * C) / 64;   // 2 (fp16 L1) or 1 (f32 L2)
    int lane = threadIdx.x & 63;
    int n = blockIdx.x * 4 + (threadIdx.x >> 6);
    if (n >= N_NODES) return;
    int head = lane >> 4;

    float Mh[ED];
#pragma unroll
    for (int d = 0; d < ED; ++d) Mh[d] = M[d * NHEAD + head];
    float ad = ad_n[(size_t)n * NHEAD + head];

    const __half2* h16 = reinterpret_cast<const __half2*>(hbuf);
    const float*   h32 = reinterpret_cast<const float*>(hbuf);

    int p0 = __builtin_amdgcn_readfirstlane(rowptr[n]);
    int p1 = __builtin_amdgcn_readfirstlane(rowptr[n + 1]);

    float acc0[FPL], acc1[FPL], acc2[FPL], acc3[FPL];
#pragma unroll
    for (int k = 0; k < FPL; ++k) { acc0[k] = 0; acc1[k] = 0; acc2[k] = 0; acc3[k] = 0; }
    float den0 = 0, den1 = 0, den2 = 0, den3 = 0;

    auto LOADH = [&](int sp, float* v) {
        if constexpr (C == 32) {
            float2 f = __half22float2(h16[(size_t)sp * 64 + lane]);
            v[0] = f.x; v[1] = f.y;
        } else {
            v[0] = h32[(size_t)sp * 64 + lane];
        }
    };
    auto EDGEW = [&](int s, int e) -> float {   // exp(leaky(alpha)) for one edge
        float a = as_n[(size_t)s * NHEAD + head] + ad;
        if (e < N_EDGES) {
            const float* er = ea + (size_t)e * ED;
            float4 A = *reinterpret_cast<const float4*>(er);
            float4 B = *reinterpret_cast<const float4*>(er + 4);
            a += A.x * Mh[0] + A.y * Mh[1] + A.z * Mh[2] + A.w * Mh[3]
               + B.x * Mh[4] + B.y * Mh[5] + B.z * Mh[6] + B.w * Mh[7];
        }
        a = (a > 0.f) ? a : 0.2f * a;
        return __expf(a);
    };

    int p = p0;
    // peel to 16B alignment so the unrolled body can use int4 loads
    while (p < p1 && (p & 3)) {
        int s0 = esrc[p];
        float w0 = EDGEW(s0, eid[p]);
        float v0[FPL]; LOADH(s0, v0);
        den0 += w0;
#pragma unroll
        for (int k = 0; k < FPL; ++k) acc0[k] += w0 * v0[k];
        ++p;
    }
    for (; p + 3 < p1; p += 4) {
        int4 sv = *reinterpret_cast<const int4*>(esrc + p);
        int4 ev = *reinterpret_cast<const int4*>(eid + p);
        float w0 = EDGEW(sv.x, ev.x), w1 = EDGEW(sv.y, ev.y);
        float w2 = EDGEW(sv.z, ev.z), w3 = EDGEW(sv.w, ev.w);
        float v0[FPL], v1[FPL], v2[FPL], v3[FPL];
        LOADH(sv.x, v0); LOADH(sv.y, v1); LOADH(sv.z, v2); LOADH(sv.w, v3);
        den0 += w0; den1 += w1; den2 += w2; den3 += w3;
#pragma unroll
        for (int k = 0; k < FPL; ++k) {
            acc0[k] += w0 * v0[k];
            acc1[k] += w1 * v1[k];
            acc2[k] += w2 * v2[k];
            acc3[k] += w3 * v3[k];
        }
    }
    for (; p < p1; ++p) {
        int s0 = esrc[p];
        float w0 = EDGEW(s0, eid[p]);
        float v0[FPL]; LOADH(s0, v0);
        den0 += w0;
#pragma unroll
        for (int k = 0; k < FPL; ++k) acc0[k] += w0 * v0[k];
    }

    float den = (den0 + den1) + (den2 + den3);
    float inv = 1.f / (den + 1e-16f);
    float v[FPL];
#pragma unroll
    for (int k = 0; k < FPL; ++k)
        v[k] = ((acc0[k] + acc1[k]) + (acc2[k] + acc3[k])) * inv;
    // head mean: lanes l, l^16, l^32, l^48 hold the same within-head column
#pragma unroll
    for (int k = 0; k < FPL; ++k) {
        v[k] += __shfl_xor(v[k], 16);
        v[k] += __shfl_xor(v[k], 32);
    }
    if (lane < 16) {
#pragma unroll
        for (int k = 0; k < FPL; ++k) {
            int c = lane * FPL + k;
            float o = 0.25f * v[k] + bias[c];
            o = (o > 0.f) ? o : expm1f(o);
            out[(size_t)n * C + c] = o;
        }
    }
}

// ---------------- launch ----------------

static inline size_t align_up(size_t x, size_t a) { return (x + a - 1) & ~(a - 1); }

extern "C" void kernel_launch(void* const* d_in, const int* in_sizes, int n_in,
                              void* d_out, int out_size, void* d_ws, size_t ws_size,
                              hipStream_t stream) {
    const float* x       = (const float*)d_in[0];
    const int*   ei      = (const int*)d_in[1];
    const float* ea      = (const float*)d_in[2];
    const float* W1      = (const float*)d_in[3];
    const float* We1     = (const float*)d_in[4];
    const float* a_src1  = (const float*)d_in[5];
    const float* a_dst1  = (const float*)d_in[6];
    const float* a_edge1 = (const float*)d_in[7];
    const float* b1      = (const float*)d_in[8];
    const float* W2      = (const float*)d_in[9];
    const float* We2     = (const float*)d_in[10];
    const float* a_src2  = (const float*)d_in[11];
    const float* a_dst2  = (const float*)d_in[12];
    const float* a_edge2 = (const float*)d_in[13];
    const float* b2      = (const float*)d_in[14];
    float* out = (float*)d_out;

    char* p = (char*)d_ws;
    auto take = [&](size_t bytes) { char* r = p; p += align_up(bytes, 256); return r; };
    int*   counts = (int*)take(sizeof(int) * N_NODES);
    int*   rowptr = (int*)take(sizeof(int) * (N_NODES + 1));
    int*   cursor = (int*)take(sizeof(int) * N_NODES);
    int*   bsum   = (int*)take(sizeof(int) * 128);
    int*   esrc   = (int*)take(sizeof(int) * ETOT);
    int*   eid    = (int*)take(sizeof(int) * ETOT);
    float* as_n   = (float*)take(sizeof(float) * N_NODES * NHEAD);
    float* ad_n   = (float*)take(sizeof(float) * N_NODES * NHEAD);
    void*  hbuf   = (void*)take((size_t)N_NODES * 128 * 2);   // fp16 L1 / f32 L2
    float* x2     = (float*)take(sizeof(float) * (size_t)N_NODES * 32);
    float* M1     = (float*)take(sizeof(float) * ED * NHEAD);
    float* M2     = (float*)take(sizeof(float) * ED * NHEAD);

    hipMemsetAsync(counts, 0, sizeof(int) * N_NODES, stream);

    int egrid = (ETOT + 255) / 256;
    count_kernel<<<egrid, 256, 0, stream>>>(ei, counts);
    scan1_kernel<<<SCAN_NB, SCAN_CHUNK, 0, stream>>>(counts, rowptr, bsum);
    scan2_kernel<<<1, 1, 0, stream>>>(bsum);
    scan3_kernel<<<SCAN_NB, SCAN_CHUNK, 0, stream>>>(rowptr, bsum, cursor);
    fill_kernel<<<egrid, 256, 0, stream>>>(ei, cursor, esrc, eid);

    make_M<<<1, 32, 0, stream>>>(We1, a_edge1, M1, 32);
    make_M<<<1, 32, 0, stream>>>(We2, a_edge2, M2, 16);

    int ngrid = N_NODES / 4;   // 25000

    // ---- layer 1: Fin=64, C=32, h stored fp16 ----
    feat_kernel<64, 32, __half><<<(N_NODES + 7) / 8, 256, 0, stream>>>(
        x, W1, a_src1, a_dst1, (__half*)hbuf, as_n, ad_n);
    gat_fused<32, __half><<<ngrid, 256, 0, stream>>>(rowptr, esrc, eid, hbuf,
                                                     as_n, ad_n, ea, M1, b1, x2);

    // ---- layer 2: Fin=32, C=16, h stored f32 ----
    feat_kernel<32, 16, float><<<(N_NODES + 15) / 16, 256, 0, stream>>>(
        x2, W2, a_src2, a_dst2, (float*)hbuf, as_n, ad_n);
    gat_fused<16, float><<<ngrid, 256, 0, stream>>>(rowptr, esrc, eid, hbuf,
                                                    as_n, ad_n, ea, M2, b2, out);
}

// Round 5
// 660.281 us; speedup vs baseline: 1.9250x; 1.3289x over previous
//
#include <hip/hip_runtime.h>
#include <hip/hip_fp16.h>
#include <math.h>

#define N_NODES 100000
#define N_EDGES 1600000
#define ETOT    (N_EDGES + N_NODES)
#define NHEAD   4
#define ED      8

// ---------------- CSR build (graph shared by both layers) ----------------

__global__ void count_kernel(const int* __restrict__ ei, int* __restrict__ counts) {
    int e = blockIdx.x * 256 + threadIdx.x;
    if (e >= ETOT) return;
    int d = (e < N_EDGES) ? ei[N_EDGES + e] : (e - N_EDGES);
    atomicAdd(&counts[d], 1);
}

#define SCAN_CHUNK 1024
#define SCAN_NB    ((N_NODES + SCAN_CHUNK - 1) / SCAN_CHUNK)   // 98

__global__ void scan1_kernel(const int* __restrict__ counts, int* __restrict__ rowptr,
                             int* __restrict__ bsum) {
    __shared__ int tmp[SCAN_CHUNK];
    int t = threadIdx.x;
    int i = blockIdx.x * SCAN_CHUNK + t;
    int v = (i < N_NODES) ? counts[i] : 0;
    tmp[t] = v;
    __syncthreads();
    for (int off = 1; off < SCAN_CHUNK; off <<= 1) {
        int x = (t >= off) ? tmp[t - off] : 0;
        __syncthreads();
        tmp[t] += x;
        __syncthreads();
    }
    if (i < N_NODES) rowptr[i] = tmp[t] - v;
    if (t == SCAN_CHUNK - 1) bsum[blockIdx.x] = tmp[t];
}

__global__ void scan2_kernel(int* __restrict__ bsum) {
    if (threadIdx.x == 0 && blockIdx.x == 0) {
        int run = 0;
        for (int b = 0; b < SCAN_NB; ++b) { int t = bsum[b]; bsum[b] = run; run += t; }
    }
}

__global__ void scan3_kernel(int* __restrict__ rowptr, const int* __restrict__ bsum,
                             int* __restrict__ cursor) {
    int i = blockIdx.x * SCAN_CHUNK + threadIdx.x;
    if (i < N_NODES) {
        int v = rowptr[i] + bsum[blockIdx.x];
        rowptr[i] = v;
        cursor[i] = v;
    }
    if (i == 0) rowptr[N_NODES] = ETOT;
}

// one 16B scatter per edge: {src, eid, dst, 0}
__global__ void fill_kernel(const int* __restrict__ ei, int* __restrict__ cursor,
                            int4* __restrict__ ecsr) {
    int e = blockIdx.x * 256 + threadIdx.x;
    if (e >= ETOT) return;
    int s, d;
    if (e < N_EDGES) { s = ei[e]; d = ei[N_EDGES + e]; }
    else             { s = e - N_EDGES; d = s; }
    int p = atomicAdd(&cursor[d], 1);
    ecsr[p] = make_int4(s, e, d, 0);
}

// ---------------- fold We/a_edge into M[8][4] ----------------

__global__ void make_M(const float* __restrict__ We, const float* __restrict__ a_edge,
                       float* __restrict__ M, int C) {
    int t = threadIdx.x;
    if (t >= ED * NHEAD) return;
    int d = t >> 2, h = t & 3;
    float s = 0.f;
    for (int c = 0; c < C; ++c) s += We[d * (NHEAD * C) + h * C + c] * a_edge[h * C + c];
    M[d * NHEAD + h] = s;
}

// ---------------- h = x @ W + per-node attention scalars ----------------

template <int FIN, int C, typename HT>
__global__ __launch_bounds__(256) void feat_kernel(
    const float* __restrict__ x, const float* __restrict__ W,
    const float* __restrict__ a_src, const float* __restrict__ a_dst,
    HT* __restrict__ h, float* __restrict__ as_n, float* __restrict__ ad_n) {
    constexpr int CH  = NHEAD * C;
    constexpr int TPN = CH / 4;        // threads per node
    constexpr int NPB = 256 / TPN;     // nodes per block
    __shared__ float xs[NPB][FIN + 1];
    int t = threadIdx.x;
    int ln = t / TPN;
    int ct = t % TPN;
    int nbase = blockIdx.x * NPB;
    for (int i = t; i < NPB * FIN; i += 256) {
        int nn = i / FIN, dd = i % FIN;
        int gn = nbase + nn;
        xs[nn][dd] = (gn < N_NODES) ? x[(size_t)gn * FIN + dd] : 0.f;
    }
    __syncthreads();
    int n = nbase + ln;
    if (n >= N_NODES) return;
    float a0 = 0, a1 = 0, a2 = 0, a3 = 0;
    const float* wp = W + ct * 4;
#pragma unroll
    for (int dd = 0; dd < FIN; ++dd) {
        float xv = xs[ln][dd];
        float4 wv = *reinterpret_cast<const float4*>(wp + (size_t)dd * CH);
        a0 += xv * wv.x; a1 += xv * wv.y; a2 += xv * wv.z; a3 += xv * wv.w;
    }
    if constexpr (sizeof(HT) == 2) {
        __half2 p01 = __floats2half2_rn(a0, a1);
        __half2 p23 = __floats2half2_rn(a2, a3);
        __half2* hp = reinterpret_cast<__half2*>(
            reinterpret_cast<__half*>(h) + (size_t)n * CH + ct * 4);
        hp[0] = p01; hp[1] = p23;
    } else {
        *reinterpret_cast<float4*>(reinterpret_cast<float*>(h) + (size_t)n * CH + ct * 4)
            = make_float4(a0, a1, a2, a3);
    }
    int c4 = ct * 4;
    float sa = a0 * a_src[c4] + a1 * a_src[c4 + 1] + a2 * a_src[c4 + 2] + a3 * a_src[c4 + 3];
    float sd = a0 * a_dst[c4] + a1 * a_dst[c4 + 1] + a2 * a_dst[c4 + 2] + a3 * a_dst[c4 + 3];
    constexpr int GRP = C / 4;
#pragma unroll
    for (int off = GRP / 2; off > 0; off >>= 1) {
        sa += __shfl_xor(sa, off);
        sd += __shfl_xor(sd, off);
    }
    if ((ct & (GRP - 1)) == 0) {
        int head = ct / GRP;
        as_n[(size_t)n * NHEAD + head] = sa;
        ad_n[(size_t)n * NHEAD + head] = sd;
    }
}

// ---------------- edge-weight pass, CSR order: coalesced read+write, no atomics ----
// w[p][h] = exp(leaky(as[src]+ad[dst]+ea[eid]·M)). dst is monotone in p -> ad gather
// is effectively sequential; as_n table (1.6MB) is L2-resident; ea gather hits L3.

__global__ __launch_bounds__(256) void alpha_csr(
    const int4* __restrict__ ecsr, const float* __restrict__ ea,
    const float4* __restrict__ as4, const float4* __restrict__ ad4,
    const float* __restrict__ M, float4* __restrict__ wbuf) {
    int p = blockIdx.x * 256 + threadIdx.x;
    if (p >= ETOT) return;
    int4 r = ecsr[p];
    int s = r.x, e = r.y, d = r.z;
    float4 A = as4[s];
    float4 B = ad4[d];
    float a0 = A.x + B.x, a1 = A.y + B.y, a2 = A.z + B.z, a3 = A.w + B.w;
    if (e < N_EDGES) {
        const float* er = ea + (size_t)e * ED;
        float4 E0 = *reinterpret_cast<const float4*>(er);
        float4 E1 = *reinterpret_cast<const float4*>(er + 4);
        float ev[8] = {E0.x, E0.y, E0.z, E0.w, E1.x, E1.y, E1.z, E1.w};
#pragma unroll
        for (int dd = 0; dd < 8; ++dd) {
            float xv = ev[dd];
            a0 += xv * M[dd * 4 + 0];
            a1 += xv * M[dd * 4 + 1];
            a2 += xv * M[dd * 4 + 2];
            a3 += xv * M[dd * 4 + 3];
        }
    }
    a0 = (a0 > 0.f) ? a0 : 0.2f * a0;
    a1 = (a1 > 0.f) ? a1 : 0.2f * a1;
    a2 = (a2 > 0.f) ? a2 : 0.2f * a2;
    a3 = (a3 > 0.f) ? a3 : 0.2f * a3;
    wbuf[p] = make_float4(__expf(a0), __expf(a1), __expf(a2), __expf(a3));
}

// ---------------- aggregation: one wave per dst node, predicated unroll-8 ----------
// Per edge: 4B src + 4B weight + one h-row gather + 2 FMA. Index-clamping keeps
// 8 gather chains in flight even in row tails.

template <int C, typename HT>
__global__ __launch_bounds__(256) void gat_agg(
    const int* __restrict__ rowptr, const int4* __restrict__ ecsr,
    const float* __restrict__ wbuf, const void* __restrict__ hbuf,
    const float* __restrict__ bias, float* __restrict__ out) {
    constexpr int FPL = (NHEAD * C) / 64;   // 2 (fp16 L1) or 1 (f32 L2)
    int lane = threadIdx.x & 63;
    int n = blockIdx.x * 4 + (threadIdx.x >> 6);
    if (n >= N_NODES) return;
    int head = lane >> 4;

    const __half2* h16 = reinterpret_cast<const __half2*>(hbuf);
    const float*   h32 = reinterpret_cast<const float*>(hbuf);

    int p0 = __builtin_amdgcn_readfirstlane(rowptr[n]);
    int p1 = __builtin_amdgcn_readfirstlane(rowptr[n + 1]);

    float acc[8][FPL];
    float den[8];
#pragma unroll
    for (int j = 0; j < 8; ++j) {
        den[j] = 0.f;
#pragma unroll
        for (int k = 0; k < FPL; ++k) acc[j][k] = 0.f;
    }

    for (int p = p0; p < p1; p += 8) {
        int   sp[8];
        float w[8];
#pragma unroll
        for (int j = 0; j < 8; ++j) {
            int pp = p + j;
            bool ok = pp < p1;
            int q = ok ? pp : (p1 - 1);
            sp[j] = ecsr[q].x;
            float wv = wbuf[(size_t)q * 4 + head];
            w[j] = ok ? wv : 0.f;
        }
#pragma unroll
        for (int j = 0; j < 8; ++j) {
            float v[FPL];
            if constexpr (C == 32) {
                float2 f = __half22float2(h16[(size_t)sp[j] * 64 + lane]);
                v[0] = f.x; v[1] = f.y;
            } else {
                v[0] = h32[(size_t)sp[j] * 64 + lane];
            }
            den[j] += w[j];
#pragma unroll
            for (int k = 0; k < FPL; ++k) acc[j][k] += w[j] * v[k];
        }
    }

    float dsum = ((den[0] + den[1]) + (den[2] + den[3]))
               + ((den[4] + den[5]) + (den[6] + den[7]));
    float inv = 1.f / (dsum + 1e-16f);
    float v[FPL];
#pragma unroll
    for (int k = 0; k < FPL; ++k) {
        float a = ((acc[0][k] + acc[1][k]) + (acc[2][k] + acc[3][k]))
                + ((acc[4][k] + acc[5][k]) + (acc[6][k] + acc[7][k]));
        v[k] = a * inv;
    }
    // head mean: lanes l, l^16, l^32, l^48 hold the same within-head column
#pragma unroll
    for (int k = 0; k < FPL; ++k) {
        v[k] += __shfl_xor(v[k], 16);
        v[k] += __shfl_xor(v[k], 32);
    }
    if (lane < 16) {
#pragma unroll
        for (int k = 0; k < FPL; ++k) {
            int c = lane * FPL + k;
            float o = 0.25f * v[k] + bias[c];
            o = (o > 0.f) ? o : expm1f(o);
            out[(size_t)n * C + c] = o;
        }
    }
}

// ---------------- launch ----------------

static inline size_t align_up(size_t x, size_t a) { return (x + a - 1) & ~(a - 1); }

extern "C" void kernel_launch(void* const* d_in, const int* in_sizes, int n_in,
                              void* d_out, int out_size, void* d_ws, size_t ws_size,
                              hipStream_t stream) {
    const float* x       = (const float*)d_in[0];
    const int*   ei      = (const int*)d_in[1];
    const float* ea      = (const float*)d_in[2];
    const float* W1      = (const float*)d_in[3];
    const float* We1     = (const float*)d_in[4];
    const float* a_src1  = (const float*)d_in[5];
    const float* a_dst1  = (const float*)d_in[6];
    const float* a_edge1 = (const float*)d_in[7];
    const float* b1      = (const float*)d_in[8];
    const float* W2      = (const float*)d_in[9];
    const float* We2     = (const float*)d_in[10];
    const float* a_src2  = (const float*)d_in[11];
    const float* a_dst2  = (const float*)d_in[12];
    const float* a_edge2 = (const float*)d_in[13];
    const float* b2      = (const float*)d_in[14];
    float* out = (float*)d_out;

    char* p = (char*)d_ws;
    auto take = [&](size_t bytes) { char* r = p; p += align_up(bytes, 256); return r; };
    int*    counts = (int*)take(sizeof(int) * N_NODES);
    int*    rowptr = (int*)take(sizeof(int) * (N_NODES + 1));
    int*    cursor = (int*)take(sizeof(int) * N_NODES);
    int*    bsum   = (int*)take(sizeof(int) * 128);
    int4*   ecsr   = (int4*)take(sizeof(int4) * ETOT);          // 27.2 MB
    float4* wbuf   = (float4*)take(sizeof(float4) * ETOT);      // 27.2 MB
    float*  as_n   = (float*)take(sizeof(float) * N_NODES * NHEAD);
    float*  ad_n   = (float*)take(sizeof(float) * N_NODES * NHEAD);
    void*   hbuf   = (void*)take((size_t)N_NODES * 128 * 2);    // fp16 L1 / f32 L2
    float*  x2     = (float*)take(sizeof(float) * (size_t)N_NODES * 32);
    float*  M1     = (float*)take(sizeof(float) * ED * NHEAD);
    float*  M2     = (float*)take(sizeof(float) * ED * NHEAD);

    hipMemsetAsync(counts, 0, sizeof(int) * N_NODES, stream);

    int egrid = (ETOT + 255) / 256;
    count_kernel<<<egrid, 256, 0, stream>>>(ei, counts);
    scan1_kernel<<<SCAN_NB, SCAN_CHUNK, 0, stream>>>(counts, rowptr, bsum);
    scan2_kernel<<<1, 1, 0, stream>>>(bsum);
    scan3_kernel<<<SCAN_NB, SCAN_CHUNK, 0, stream>>>(rowptr, bsum, cursor);
    fill_kernel<<<egrid, 256, 0, stream>>>(ei, cursor, ecsr);

    make_M<<<1, 32, 0, stream>>>(We1, a_edge1, M1, 32);
    make_M<<<1, 32, 0, stream>>>(We2, a_edge2, M2, 16);

    int ngrid = N_NODES / 4;   // 25000

    // ---- layer 1: Fin=64, C=32, h stored fp16 ----
    feat_kernel<64, 32, __half><<<(N_NODES + 7) / 8, 256, 0, stream>>>(
        x, W1, a_src1, a_dst1, (__half*)hbuf, as_n, ad_n);
    alpha_csr<<<egrid, 256, 0, stream>>>(ecsr, ea, (const float4*)as_n,
                                         (const float4*)ad_n, M1, wbuf);
    gat_agg<32, __half><<<ngrid, 256, 0, stream>>>(rowptr, ecsr, (const float*)wbuf,
                                                   hbuf, b1, x2);

    // ---- layer 2: Fin=32, C=16, h stored f32 ----
    feat_kernel<32, 16, float><<<(N_NODES + 15) / 16, 256, 0, stream>>>(
        x2, W2, a_src2, a_dst2, (float*)hbuf, as_n, ad_n);
    alpha_csr<<<egrid, 256, 0, stream>>>(ecsr, ea, (const float4*)as_n,
                                         (const float4*)ad_n, M2, wbuf);
    gat_agg<16, float><<<ngrid, 256, 0, stream>>>(rowptr, ecsr, (const float*)wbuf,
                                                  hbuf, b2, out);
}

// Round 6
// 597.820 us; speedup vs baseline: 2.1261x; 1.1045x over previous
//
#include <hip/hip_runtime.h>
#include <hip/hip_fp16.h>
#include <math.h>

#define N_NODES 100000
#define N_EDGES 1600000
#define ETOT    (N_EDGES + N_NODES)
#define NHEAD   4
#define ED      8

// ---------------- CSR build ----------------

__global__ void count_kernel(const int* __restrict__ ei, int* __restrict__ counts) {
    int e = blockIdx.x * 256 + threadIdx.x;
    if (e >= ETOT) return;
    int d = (e < N_EDGES) ? ei[N_EDGES + e] : (e - N_EDGES);
    atomicAdd(&counts[d], 1);
}

#define SCAN_CHUNK 1024
#define SCAN_NB    ((N_NODES + SCAN_CHUNK - 1) / SCAN_CHUNK)   // 98

__global__ void scan1_kernel(const int* __restrict__ counts, int* __restrict__ rowptr,
                             int* __restrict__ bsum) {
    __shared__ int tmp[SCAN_CHUNK];
    int t = threadIdx.x;
    int i = blockIdx.x * SCAN_CHUNK + t;
    int v = (i < N_NODES) ? counts[i] : 0;
    tmp[t] = v;
    __syncthreads();
    for (int off = 1; off < SCAN_CHUNK; off <<= 1) {
        int x = (t >= off) ? tmp[t - off] : 0;
        __syncthreads();
        tmp[t] += x;
        __syncthreads();
    }
    if (i < N_NODES) rowptr[i] = tmp[t] - v;
    if (t == SCAN_CHUNK - 1) bsum[blockIdx.x] = tmp[t];
}

__global__ void scan2_kernel(int* __restrict__ bsum) {
    if (threadIdx.x == 0 && blockIdx.x == 0) {
        int run = 0;
        for (int b = 0; b < SCAN_NB; ++b) { int t = bsum[b]; bsum[b] = run; run += t; }
    }
}

__global__ void scan3_kernel(int* __restrict__ rowptr, const int* __restrict__ bsum,
                             int* __restrict__ cursor) {
    int i = blockIdx.x * SCAN_CHUNK + threadIdx.x;
    if (i < N_NODES) {
        int v = rowptr[i] + bsum[blockIdx.x];
        rowptr[i] = v;
        cursor[i] = v;
    }
    if (i == 0) rowptr[N_NODES] = ETOT;
}

// ---------------- fold We/a_edge into M[8][4] ----------------

__global__ void make_M(const float* __restrict__ We, const float* __restrict__ a_edge,
                       float* __restrict__ M, int C) {
    int t = threadIdx.x;
    if (t >= ED * NHEAD) return;
    int d = t >> 2, h = t & 3;
    float s = 0.f;
    for (int c = 0; c < C; ++c) s += We[d * (NHEAD * C) + h * C + c] * a_edge[h * C + c];
    M[d * NHEAD + h] = s;
}

// ---------------- fill: ONE 32B scatter per edge carrying src + ae for BOTH layers --
// record layout (32B): [0:4) src | [4:12) ae1 as 4xfp16 | [12:20) ae2 as 4xfp16 | pad

__global__ __launch_bounds__(256) void fill_kernel(
    const int* __restrict__ ei, const float* __restrict__ ea,
    const float* __restrict__ M1, const float* __restrict__ M2,
    int* __restrict__ cursor, uint* __restrict__ rec) {
    int e = blockIdx.x * 256 + threadIdx.x;
    if (e >= ETOT) return;
    int s, d;
    float a10 = 0, a11 = 0, a12 = 0, a13 = 0;
    float a20 = 0, a21 = 0, a22 = 0, a23 = 0;
    if (e < N_EDGES) {
        s = ei[e]; d = ei[N_EDGES + e];
        const float* er = ea + (size_t)e * ED;
        float4 E0 = *reinterpret_cast<const float4*>(er);
        float4 E1 = *reinterpret_cast<const float4*>(er + 4);
        float ev[8] = {E0.x, E0.y, E0.z, E0.w, E1.x, E1.y, E1.z, E1.w};
#pragma unroll
        for (int dd = 0; dd < 8; ++dd) {
            float xv = ev[dd];
            a10 += xv * M1[dd * 4 + 0]; a11 += xv * M1[dd * 4 + 1];
            a12 += xv * M1[dd * 4 + 2]; a13 += xv * M1[dd * 4 + 3];
            a20 += xv * M2[dd * 4 + 0]; a21 += xv * M2[dd * 4 + 1];
            a22 += xv * M2[dd * 4 + 2]; a23 += xv * M2[dd * 4 + 3];
        }
    } else {
        s = e - N_EDGES; d = s;     // self-loop: edge_attr = 0 -> ae = 0
    }
    int p = atomicAdd(&cursor[d], 1);
    __half2 h10 = __floats2half2_rn(a10, a11);
    __half2 h11 = __floats2half2_rn(a12, a13);
    __half2 h20 = __floats2half2_rn(a20, a21);
    __half2 h21 = __floats2half2_rn(a22, a23);
    uint4 lo;
    lo.x = (uint)s;
    lo.y = *reinterpret_cast<uint*>(&h10);
    lo.z = *reinterpret_cast<uint*>(&h11);
    lo.w = *reinterpret_cast<uint*>(&h20);
    uint* rp = rec + (size_t)p * 8;
    *reinterpret_cast<uint4*>(rp) = lo;
    rp[4] = *reinterpret_cast<uint*>(&h21);
}

// ---------------- h = x @ W + per-node attention scalars ----------------

template <int FIN, int C, typename HT>
__global__ __launch_bounds__(256) void feat_kernel(
    const float* __restrict__ x, const float* __restrict__ W,
    const float* __restrict__ a_src, const float* __restrict__ a_dst,
    HT* __restrict__ h, float* __restrict__ as_n, float* __restrict__ ad_n) {
    constexpr int CH  = NHEAD * C;
    constexpr int TPN = CH / 4;        // threads per node
    constexpr int NPB = 256 / TPN;     // nodes per block
    __shared__ float xs[NPB][FIN + 1];
    int t = threadIdx.x;
    int ln = t / TPN;
    int ct = t % TPN;
    int nbase = blockIdx.x * NPB;
    for (int i = t; i < NPB * FIN; i += 256) {
        int nn = i / FIN, dd = i % FIN;
        int gn = nbase + nn;
        xs[nn][dd] = (gn < N_NODES) ? x[(size_t)gn * FIN + dd] : 0.f;
    }
    __syncthreads();
    int n = nbase + ln;
    if (n >= N_NODES) return;
    float a0 = 0, a1 = 0, a2 = 0, a3 = 0;
    const float* wp = W + ct * 4;
#pragma unroll
    for (int dd = 0; dd < FIN; ++dd) {
        float xv = xs[ln][dd];
        float4 wv = *reinterpret_cast<const float4*>(wp + (size_t)dd * CH);
        a0 += xv * wv.x; a1 += xv * wv.y; a2 += xv * wv.z; a3 += xv * wv.w;
    }
    if constexpr (sizeof(HT) == 2) {
        __half2 p01 = __floats2half2_rn(a0, a1);
        __half2 p23 = __floats2half2_rn(a2, a3);
        __half2* hp = reinterpret_cast<__half2*>(
            reinterpret_cast<__half*>(h) + (size_t)n * CH + ct * 4);
        hp[0] = p01; hp[1] = p23;
    } else {
        *reinterpret_cast<float4*>(reinterpret_cast<float*>(h) + (size_t)n * CH + ct * 4)
            = make_float4(a0, a1, a2, a3);
    }
    int c4 = ct * 4;
    float sa = a0 * a_src[c4] + a1 * a_src[c4 + 1] + a2 * a_src[c4 + 2] + a3 * a_src[c4 + 3];
    float sd = a0 * a_dst[c4] + a1 * a_dst[c4 + 1] + a2 * a_dst[c4 + 2] + a3 * a_dst[c4 + 3];
    constexpr int GRP = C / 4;
#pragma unroll
    for (int off = GRP / 2; off > 0; off >>= 1) {
        sa += __shfl_xor(sa, off);
        sd += __shfl_xor(sd, off);
    }
    if ((ct & (GRP - 1)) == 0) {
        int head = ct / GRP;
        as_n[(size_t)n * NHEAD + head] = sa;
        ad_n[(size_t)n * NHEAD + head] = sd;
    }
}

// ---------------- fused aggregation: one wave per dst node ----------------
// Per edge: 32B record (broadcast, p-sequential), 4B as_n gather, h-row gather,
// w = exp(leaky(as+ad+ae)); predicated unroll-8 keeps 8 chains in flight.

template <int C, int AEOFF>
__global__ __launch_bounds__(256) void gat_agg(
    const int* __restrict__ rowptr, const char* __restrict__ rec,
    const __half* __restrict__ hbuf, const float* __restrict__ as_n,
    const float* __restrict__ ad_n, const float* __restrict__ bias,
    float* __restrict__ out) {
    constexpr int FPL = (NHEAD * C) / 64;   // 2 (C=32) or 1 (C=16)
    int lane = threadIdx.x & 63;
    int n = blockIdx.x * 4 + (threadIdx.x >> 6);
    if (n >= N_NODES) return;
    int head = lane >> 4;

    float ad = ad_n[(size_t)n * NHEAD + head];
    const __half2* h2p = reinterpret_cast<const __half2*>(hbuf);

    int p0 = __builtin_amdgcn_readfirstlane(rowptr[n]);
    int p1 = __builtin_amdgcn_readfirstlane(rowptr[n + 1]);

    float acc[8][FPL];
    float den[8];
#pragma unroll
    for (int j = 0; j < 8; ++j) {
        den[j] = 0.f;
#pragma unroll
        for (int k = 0; k < FPL; ++k) acc[j][k] = 0.f;
    }

    for (int p = p0; p < p1; p += 8) {
        int   sp[8];
        float w[8];
#pragma unroll
        for (int j = 0; j < 8; ++j) {
            int pp = p + j;
            bool ok = pp < p1;
            int q = ok ? pp : (p1 - 1);
            const char* rp = rec + (size_t)q * 32;
            sp[j] = *reinterpret_cast<const int*>(rp);
            __half aeh = *reinterpret_cast<const __half*>(rp + AEOFF + 2 * head);
            float a = as_n[(size_t)sp[j] * NHEAD + head] + ad + __half2float(aeh);
            a = (a > 0.f) ? a : 0.2f * a;
            float wv = __expf(a);
            w[j] = ok ? wv : 0.f;
        }
#pragma unroll
        for (int j = 0; j < 8; ++j) {
            float v[FPL];
            if constexpr (C == 32) {
                float2 f = __half22float2(h2p[(size_t)sp[j] * 64 + lane]);
                v[0] = f.x; v[1] = f.y;
            } else {
                v[0] = __half2float(hbuf[(size_t)sp[j] * 64 + lane]);
            }
            den[j] += w[j];
#pragma unroll
            for (int k = 0; k < FPL; ++k) acc[j][k] += w[j] * v[k];
        }
    }

    float dsum = ((den[0] + den[1]) + (den[2] + den[3]))
               + ((den[4] + den[5]) + (den[6] + den[7]));
    float inv = 1.f / (dsum + 1e-16f);
    float v[FPL];
#pragma unroll
    for (int k = 0; k < FPL; ++k) {
        float a = ((acc[0][k] + acc[1][k]) + (acc[2][k] + acc[3][k]))
                + ((acc[4][k] + acc[5][k]) + (acc[6][k] + acc[7][k]));
        v[k] = a * inv;
    }
    // head mean: lanes l, l^16, l^32, l^48 hold the same within-head column
#pragma unroll
    for (int k = 0; k < FPL; ++k) {
        v[k] += __shfl_xor(v[k], 16);
        v[k] += __shfl_xor(v[k], 32);
    }
    if (lane < 16) {
#pragma unroll
        for (int k = 0; k < FPL; ++k) {
            int c = lane * FPL + k;
            float o = 0.25f * v[k] + bias[c];
            o = (o > 0.f) ? o : expm1f(o);
            out[(size_t)n * C + c] = o;
        }
    }
}

// ---------------- launch ----------------

static inline size_t align_up(size_t x, size_t a) { return (x + a - 1) & ~(a - 1); }

extern "C" void kernel_launch(void* const* d_in, const int* in_sizes, int n_in,
                              void* d_out, int out_size, void* d_ws, size_t ws_size,
                              hipStream_t stream) {
    const float* x       = (const float*)d_in[0];
    const int*   ei      = (const int*)d_in[1];
    const float* ea      = (const float*)d_in[2];
    const float* W1      = (const float*)d_in[3];
    const float* We1     = (const float*)d_in[4];
    const float* a_src1  = (const float*)d_in[5];
    const float* a_dst1  = (const float*)d_in[6];
    const float* a_edge1 = (const float*)d_in[7];
    const float* b1      = (const float*)d_in[8];
    const float* W2      = (const float*)d_in[9];
    const float* We2     = (const float*)d_in[10];
    const float* a_src2  = (const float*)d_in[11];
    const float* a_dst2  = (const float*)d_in[12];
    const float* a_edge2 = (const float*)d_in[13];
    const float* b2      = (const float*)d_in[14];
    float* out = (float*)d_out;

    char* p = (char*)d_ws;
    auto take = [&](size_t bytes) { char* r = p; p += align_up(bytes, 256); return r; };
    int*   counts = (int*)take(sizeof(int) * N_NODES);
    int*   rowptr = (int*)take(sizeof(int) * (N_NODES + 1));
    int*   cursor = (int*)take(sizeof(int) * N_NODES);
    int*   bsum   = (int*)take(sizeof(int) * 128);
    char*  rec    = (char*)take((size_t)ETOT * 32);             // 54.4 MB
    float* as_n   = (float*)take(sizeof(float) * N_NODES * NHEAD);
    float* ad_n   = (float*)take(sizeof(float) * N_NODES * NHEAD);
    __half* hbuf  = (__half*)take((size_t)N_NODES * 128 * 2);   // 25.6 MB
    float* x2     = (float*)take(sizeof(float) * (size_t)N_NODES * 32);
    float* M1     = (float*)take(sizeof(float) * ED * NHEAD);
    float* M2     = (float*)take(sizeof(float) * ED * NHEAD);

    hipMemsetAsync(counts, 0, sizeof(int) * N_NODES, stream);

    int egrid = (ETOT + 255) / 256;
    count_kernel<<<egrid, 256, 0, stream>>>(ei, counts);
    scan1_kernel<<<SCAN_NB, SCAN_CHUNK, 0, stream>>>(counts, rowptr, bsum);
    scan2_kernel<<<1, 1, 0, stream>>>(bsum);
    scan3_kernel<<<SCAN_NB, SCAN_CHUNK, 0, stream>>>(rowptr, bsum, cursor);

    make_M<<<1, 32, 0, stream>>>(We1, a_edge1, M1, 32);
    make_M<<<1, 32, 0, stream>>>(We2, a_edge2, M2, 16);

    fill_kernel<<<egrid, 256, 0, stream>>>(ei, ea, M1, M2, cursor, (uint*)rec);

    int ngrid = N_NODES / 4;   // 25000

    // ---- layer 1: Fin=64, C=32, h fp16 ----
    feat_kernel<64, 32, __half><<<(N_NODES + 7) / 8, 256, 0, stream>>>(
        x, W1, a_src1, a_dst1, hbuf, as_n, ad_n);
    gat_agg<32, 4><<<ngrid, 256, 0, stream>>>(rowptr, rec, hbuf, as_n, ad_n, b1, x2);

    // ---- layer 2: Fin=32, C=16, h fp16 ----
    feat_kernel<32, 16, __half><<<(N_NODES + 15) / 16, 256, 0, stream>>>(
        x2, W2, a_src2, a_dst2, hbuf, as_n, ad_n);
    gat_agg<16, 12><<<ngrid, 256, 0, stream>>>(rowptr, rec, hbuf, as_n, ad_n, b2, out);
}